// Round 1
// baseline (266.180 us; speedup 1.0000x reference)
//
#include <hip/hip_runtime.h>
#include <math.h>

#define CDIM 192
#define NHEADS 4
#define HC 48
#define DD 28

// C[M,N] = (A[M,K] @ B[K,N] + bias[N]) * alpha
// BM=BN=64, BK=16, 256 threads, 4x4 microtile per thread.
__global__ __launch_bounds__(256) void sgemm_bias(
    const float* __restrict__ A, const float* __restrict__ B,
    const float* __restrict__ bias, float* __restrict__ C,
    int M, int N, int K, float alpha)
{
  __shared__ float As[16][65];   // [k][m], padded to dodge bank conflicts
  __shared__ float Bs[16][68];   // [k][n], pad 4 keeps float4 alignment

  const int tid = threadIdx.x;
  const int tr = tid / 16;       // 0..15 -> output rows tr*4..+3
  const int tc = tid % 16;       // 0..15 -> output cols tc*4..+3
  const int m0 = blockIdx.x * 64;
  const int n0 = blockIdx.y * 64;

  // A-tile load mapping: each thread loads float4 along K
  const int arow = tid / 4;           // 0..63
  const int akk  = (tid % 4) * 4;     // 0,4,8,12
  // B-tile load mapping: each thread loads float4 along N
  const int bkk  = tid / 16;          // 0..15
  const int bnn  = (tid % 16) * 4;    // 0..60

  float acc[4][4] = {};

  for (int k0 = 0; k0 < K; k0 += 16) {
    const float4 a4 = *reinterpret_cast<const float4*>(
        &A[(size_t)(m0 + arow) * K + (k0 + akk)]);
    As[akk + 0][arow] = a4.x;
    As[akk + 1][arow] = a4.y;
    As[akk + 2][arow] = a4.z;
    As[akk + 3][arow] = a4.w;
    const float4 b4 = *reinterpret_cast<const float4*>(
        &B[(size_t)(k0 + bkk) * N + (n0 + bnn)]);
    Bs[bkk][bnn + 0] = b4.x;
    Bs[bkk][bnn + 1] = b4.y;
    Bs[bkk][bnn + 2] = b4.z;
    Bs[bkk][bnn + 3] = b4.w;
    __syncthreads();

#pragma unroll
    for (int kk = 0; kk < 16; ++kk) {
      float ra[4], rb[4];
#pragma unroll
      for (int i = 0; i < 4; ++i) ra[i] = As[kk][tr * 4 + i];
#pragma unroll
      for (int j = 0; j < 4; ++j) rb[j] = Bs[kk][tc * 4 + j];
#pragma unroll
      for (int i = 0; i < 4; ++i)
#pragma unroll
        for (int j = 0; j < 4; ++j) acc[i][j] += ra[i] * rb[j];
    }
    __syncthreads();
  }

#pragma unroll
  for (int i = 0; i < 4; ++i) {
    const size_t row = (size_t)(m0 + tr * 4 + i) * N;
#pragma unroll
    for (int j = 0; j < 4; ++j) {
      const int n = n0 + tc * 4 + j;
      C[row + n] = (acc[i][j] + bias[n]) * alpha;
    }
  }
}

// One 64-lane block per voxel. Lane owns 3 channels (c0 = lane*3).
// Head = lane/16 (48 channels per head = 16 lanes). 27-key windowed
// attention; OOB slots: logit = 0 (k padded with zeros, counted in the
// softmax denominator), v = 0 (skipped in the weighted sum).
__global__ __launch_bounds__(64) void attn3d(
    const float* __restrict__ q, const float* __restrict__ kvbuf,
    float* __restrict__ y)
{
  const int vox = blockIdx.x;
  const int wx = vox % DD;
  const int hy = (vox / DD) % DD;
  const int dz0 = vox / (DD * DD);
  const int lane = threadIdx.x;
  const int c0 = lane * 3;

  const float* qp = &q[(size_t)vox * CDIM + c0];
  const float q0 = qp[0], q1 = qp[1], q2 = qp[2];

  float logits[27];
  int nvox[27];

#pragma unroll
  for (int dz = 0; dz < 3; ++dz)
#pragma unroll
    for (int dy = 0; dy < 3; ++dy)
#pragma unroll
      for (int dx = 0; dx < 3; ++dx) {
        const int ki = (dz * 3 + dy) * 3 + dx;
        const int zz = dz0 + dz - 1, yy = hy + dy - 1, xx = wx + dx - 1;
        const bool ok = (unsigned)zz < DD && (unsigned)yy < DD && (unsigned)xx < DD;
        const int nv = (zz * DD + yy) * DD + xx;
        float lg = 0.f;
        if (ok) {  // wave-uniform branch
          const float* kp = &kvbuf[(size_t)nv * (2 * CDIM) + c0];
          float p = q0 * kp[0] + q1 * kp[1] + q2 * kp[2];
          p += __shfl_xor(p, 1);
          p += __shfl_xor(p, 2);
          p += __shfl_xor(p, 4);
          p += __shfl_xor(p, 8);
          lg = p;  // per-head (16-lane group) dot product
        }
        nvox[ki] = ok ? nv : -1;
        logits[ki] = lg;
      }

  float m = logits[0];
#pragma unroll
  for (int i = 1; i < 27; ++i) m = fmaxf(m, logits[i]);
  float s = 0.f;
  float p[27];
#pragma unroll
  for (int i = 0; i < 27; ++i) { p[i] = __expf(logits[i] - m); s += p[i]; }
  const float inv = 1.f / s;

  float a0 = 0.f, a1 = 0.f, a2 = 0.f;
#pragma unroll
  for (int i = 0; i < 27; ++i) {
    if (nvox[i] >= 0) {  // wave-uniform
      const float* vp = &kvbuf[(size_t)nvox[i] * (2 * CDIM) + CDIM + c0];
      const float w = p[i] * inv;
      a0 += w * vp[0];
      a1 += w * vp[1];
      a2 += w * vp[2];
    }
  }
  float* yp = &y[(size_t)vox * CDIM + c0];
  yp[0] = a0; yp[1] = a1; yp[2] = a2;
}

extern "C" void kernel_launch(void* const* d_in, const int* in_sizes, int n_in,
                              void* d_out, int out_size, void* d_ws, size_t ws_size,
                              hipStream_t stream) {
  const float* x   = (const float*)d_in[0];
  const float* Wq  = (const float*)d_in[1];
  const float* bq  = (const float*)d_in[2];
  const float* Wkv = (const float*)d_in[3];
  const float* bkv = (const float*)d_in[4];
  const float* Wp  = (const float*)d_in[5];
  const float* bp  = (const float*)d_in[6];
  float* out = (float*)d_out;

  const int N = in_sizes[0] / CDIM;  // 21952 voxels

  float* qbuf  = (float*)d_ws;                   // N x 192
  float* kvbuf = qbuf + (size_t)N * CDIM;        // N x 384 (k | v)
  float* ybuf  = kvbuf + (size_t)N * 2 * CDIM;   // N x 192

  const float scale = 1.0f / sqrtf((float)HC);

  sgemm_bias<<<dim3(N / 64, CDIM / 64), 256, 0, stream>>>(
      x, Wq, bq, qbuf, N, CDIM, CDIM, scale);
  sgemm_bias<<<dim3(N / 64, (2 * CDIM) / 64), 256, 0, stream>>>(
      x, Wkv, bkv, kvbuf, N, 2 * CDIM, CDIM, 1.0f);
  attn3d<<<N, 64, 0, stream>>>(qbuf, kvbuf, ybuf);
  sgemm_bias<<<dim3(N / 64, CDIM / 64), 256, 0, stream>>>(
      ybuf, Wp, bp, out, N, CDIM, CDIM, 1.0f);
}

// Round 4
// 189.696 us; speedup vs baseline: 1.4032x; 1.4032x over previous
//
#include <hip/hip_runtime.h>
#include <math.h>

#define CDIM 192
#define DD 28
#define NVOX (DD * DD * DD)   // 21952

typedef __attribute__((ext_vector_type(8))) short bf16x8;
typedef __attribute__((ext_vector_type(4))) float f32x4;

__device__ __forceinline__ float bf2f(unsigned short u) {
  union { unsigned int i; float f; } w; w.i = ((unsigned int)u) << 16; return w.f;
}
__device__ __forceinline__ unsigned short f2bf(float f) {
  union { float ff; unsigned int i; } w; w.ff = f;
  unsigned int x = w.i;
  return (unsigned short)((x + 0x7fffu + ((x >> 16) & 1u)) >> 16);  // RNE
}

// One-shot prep: x -> bf16; weights -> bf16 transposed ([n][k]) so GEMM B
// fragments are contiguous along k.
__global__ __launch_bounds__(256) void prep(
    const float* __restrict__ x, const float* __restrict__ Wq,
    const float* __restrict__ Wkv, const float* __restrict__ Wp,
    unsigned short* __restrict__ xb, unsigned short* __restrict__ WqT,
    unsigned short* __restrict__ WkvT, unsigned short* __restrict__ WpT)
{
  const int XU = NVOX * CDIM / 8;  // 526848 units of 8 floats
  const int t = blockIdx.x * 256 + threadIdx.x;
  if (t < XU) {
    const float4 a = ((const float4*)x)[t * 2];
    const float4 b = ((const float4*)x)[t * 2 + 1];
    unsigned short o[8] = {f2bf(a.x), f2bf(a.y), f2bf(a.z), f2bf(a.w),
                           f2bf(b.x), f2bf(b.y), f2bf(b.z), f2bf(b.w)};
    *(uint4*)(&xb[t * 8]) = *(const uint4*)o;
  } else {
    int u = t - XU;
    if (u < CDIM * CDIM) {
      const int n = u / CDIM, k = u % CDIM;
      WqT[u] = f2bf(Wq[k * CDIM + n]);
    } else if ((u -= CDIM * CDIM) < 2 * CDIM * CDIM) {
      const int n = u / CDIM, k = u % CDIM;
      WkvT[u] = f2bf(Wkv[k * 2 * CDIM + n]);
    } else {
      u -= 2 * CDIM * CDIM;
      const int n = u / CDIM, k = u % CDIM;
      WpT[u] = f2bf(Wp[k * CDIM + n]);
    }
  }
}

// C[M,N] = (A @ B + bias) * alpha with A [M][192] bf16, Bt [N][192] bf16.
// 64x64 block tile, 4 waves each 32x32, K=192 resident in LDS.
// LDS row stride 200 bf16 (400 B): frag-read bank stride 4 -> 2-way only.
template<int OUT_BF16>
__global__ __launch_bounds__(256) void gemm_bf16(
    const unsigned short* __restrict__ A,
    const unsigned short* __restrict__ Bt,
    const float* __restrict__ bias,
    void* __restrict__ Cout,
    int N, float alpha)
{
  __shared__ unsigned short As[64 * 200];
  __shared__ unsigned short Bs[64 * 200];
  const int tid = threadIdx.x;
  const int n0 = blockIdx.x * 64;
  const int m0 = blockIdx.y * 64;

#pragma unroll
  for (int u = tid; u < 1536; u += 256) {  // 64 rows x 24 16B-units
    const int row = u / 24, c = (u % 24) * 8;
    *(uint4*)(&As[row * 200 + c]) =
        *(const uint4*)(&A[(size_t)(m0 + row) * CDIM + c]);
    *(uint4*)(&Bs[row * 200 + c]) =
        *(const uint4*)(&Bt[(size_t)(n0 + row) * CDIM + c]);
  }
  __syncthreads();

  const int l = tid & 63, w = tid >> 6;
  const int wm = (w >> 1) * 32, wn = (w & 1) * 32;
  const int lr = l & 15, lk = (l >> 4) * 8;

  f32x4 acc[2][2] = {};
  const unsigned short* pa = &As[(wm + lr) * 200 + lk];
  const unsigned short* pb = &Bs[(wn + lr) * 200 + lk];

#pragma unroll
  for (int k0 = 0; k0 < CDIM; k0 += 32) {
    const bf16x8 a0 = *(const bf16x8*)(pa + k0);
    const bf16x8 a1 = *(const bf16x8*)(pa + 16 * 200 + k0);
    const bf16x8 b0 = *(const bf16x8*)(pb + k0);
    const bf16x8 b1 = *(const bf16x8*)(pb + 16 * 200 + k0);
    acc[0][0] = __builtin_amdgcn_mfma_f32_16x16x32_bf16(a0, b0, acc[0][0], 0, 0, 0);
    acc[0][1] = __builtin_amdgcn_mfma_f32_16x16x32_bf16(a0, b1, acc[0][1], 0, 0, 0);
    acc[1][0] = __builtin_amdgcn_mfma_f32_16x16x32_bf16(a1, b0, acc[1][0], 0, 0, 0);
    acc[1][1] = __builtin_amdgcn_mfma_f32_16x16x32_bf16(a1, b1, acc[1][1], 0, 0, 0);
  }

  // C/D: col = lane&15, row = (lane>>4)*4 + reg   [m89-verified]
#pragma unroll
  for (int i = 0; i < 2; ++i)
#pragma unroll
    for (int j = 0; j < 2; ++j) {
      const int gc = n0 + wn + j * 16 + lr;
      const float bv = bias[gc];
#pragma unroll
      for (int r = 0; r < 4; ++r) {
        const int gr = m0 + wm + i * 16 + (l >> 4) * 4 + r;
        const float v = (acc[i][j][r] + bv) * alpha;
        if (OUT_BF16)
          ((unsigned short*)Cout)[(size_t)gr * N + gc] = f2bf(v);
        else
          ((float*)Cout)[(size_t)gr * N + gc] = v;
      }
    }
}

// One wave per voxel; lane owns 3 channels; head = lane/16 (48ch = 16 lanes).
// OOB window slots: logit = 0 (zero-padded k, still in the softmax
// denominator), v = 0 (skipped).
// blockIdx swizzled so each XCD works a contiguous z-slab (L2 locality).
__global__ __launch_bounds__(64) void attn3d_bf16(
    const unsigned short* __restrict__ q,
    const unsigned short* __restrict__ kv,
    unsigned short* __restrict__ y)
{
  const int bid = blockIdx.x;
  const int vox = (bid & 7) * (NVOX / 8) + (bid >> 3);
  const int wx = vox % DD;
  const int hy = (vox / DD) % DD;
  const int dz0 = vox / (DD * DD);
  const int lane = threadIdx.x;
  const int c0 = lane * 3;

  const unsigned short* qp = &q[(size_t)vox * CDIM + c0];
  const float q0 = bf2f(qp[0]), q1 = bf2f(qp[1]), q2 = bf2f(qp[2]);

  float logits[27];
  int nvox[27];

#pragma unroll
  for (int dz = 0; dz < 3; ++dz)
#pragma unroll
    for (int dy = 0; dy < 3; ++dy)
#pragma unroll
      for (int dx = 0; dx < 3; ++dx) {
        const int ki = (dz * 3 + dy) * 3 + dx;
        const int zz = dz0 + dz - 1, yy = hy + dy - 1, xx = wx + dx - 1;
        const bool ok = (unsigned)zz < DD && (unsigned)yy < DD && (unsigned)xx < DD;
        const int nv = (zz * DD + yy) * DD + xx;
        float lg = 0.f;
        if (ok) {  // wave-uniform
          const unsigned short* kp = &kv[(size_t)nv * (2 * CDIM) + c0];
          float p = q0 * bf2f(kp[0]) + q1 * bf2f(kp[1]) + q2 * bf2f(kp[2]);
          p += __shfl_xor(p, 1);
          p += __shfl_xor(p, 2);
          p += __shfl_xor(p, 4);
          p += __shfl_xor(p, 8);
          lg = p;
        }
        nvox[ki] = ok ? nv : -1;
        logits[ki] = lg;
      }

  float m = logits[0];
#pragma unroll
  for (int i = 1; i < 27; ++i) m = fmaxf(m, logits[i]);
  float s = 0.f;
  float p[27];
#pragma unroll
  for (int i = 0; i < 27; ++i) { p[i] = __expf(logits[i] - m); s += p[i]; }
  const float inv = 1.f / s;

  float a0 = 0.f, a1 = 0.f, a2 = 0.f;
#pragma unroll
  for (int i = 0; i < 27; ++i) {
    if (nvox[i] >= 0) {  // wave-uniform
      const unsigned short* vp = &kv[(size_t)nvox[i] * (2 * CDIM) + CDIM + c0];
      const float wgt = p[i] * inv;
      a0 += wgt * bf2f(vp[0]);
      a1 += wgt * bf2f(vp[1]);
      a2 += wgt * bf2f(vp[2]);
    }
  }
  unsigned short* yp = &y[(size_t)vox * CDIM + c0];
  yp[0] = f2bf(a0); yp[1] = f2bf(a1); yp[2] = f2bf(a2);
}

extern "C" void kernel_launch(void* const* d_in, const int* in_sizes, int n_in,
                              void* d_out, int out_size, void* d_ws, size_t ws_size,
                              hipStream_t stream) {
  const float* x   = (const float*)d_in[0];
  const float* Wq  = (const float*)d_in[1];
  const float* bq  = (const float*)d_in[2];
  const float* Wkv = (const float*)d_in[3];
  const float* bkv = (const float*)d_in[4];
  const float* Wp  = (const float*)d_in[5];
  const float* bp  = (const float*)d_in[6];
  float* out = (float*)d_out;

  unsigned short* xb   = (unsigned short*)d_ws;
  unsigned short* WqT  = xb + (size_t)NVOX * CDIM;
  unsigned short* WkvT = WqT + CDIM * CDIM;
  unsigned short* WpT  = WkvT + 2 * CDIM * CDIM;
  unsigned short* qb   = WpT + CDIM * CDIM;
  unsigned short* kvb  = qb + (size_t)NVOX * CDIM;
  unsigned short* yb   = kvb + (size_t)NVOX * 2 * CDIM;

  const float scale = 1.0f / sqrtf(48.0f);

  // total prep threads: NVOX*192/8 + 4*192*192 = 526848 + 147456 = 674304
  prep<<<674304 / 256, 256, 0, stream>>>(x, Wq, Wkv, Wp, xb, WqT, WkvT, WpT);

  gemm_bf16<1><<<dim3(CDIM / 64, NVOX / 64), 256, 0, stream>>>(
      xb, WqT, bq, qb, CDIM, scale);
  gemm_bf16<1><<<dim3(2 * CDIM / 64, NVOX / 64), 256, 0, stream>>>(
      xb, WkvT, bkv, kvb, 2 * CDIM, 1.0f);
  attn3d_bf16<<<NVOX, 64, 0, stream>>>(qb, kvb, yb);
  gemm_bf16<0><<<dim3(CDIM / 64, NVOX / 64), 256, 0, stream>>>(
      yb, WpT, bp, out, CDIM, 1.0f);
}

// Round 5
// 147.490 us; speedup vs baseline: 1.8047x; 1.2862x over previous
//
#include <hip/hip_runtime.h>
#include <math.h>

#define CDIM 192
#define DD 28
#define NVOX (DD * DD * DD)   // 21952

typedef __attribute__((ext_vector_type(8))) short bf16x8;
typedef __attribute__((ext_vector_type(4))) float f32x4;

__device__ __forceinline__ float bf2f(unsigned short u) {
  union { unsigned int i; float f; } w; w.i = ((unsigned int)u) << 16; return w.f;
}
__device__ __forceinline__ float blo(unsigned int u) {
  union { unsigned int i; float f; } w; w.i = u << 16; return w.f;
}
__device__ __forceinline__ float bhi(unsigned int u) {
  union { unsigned int i; float f; } w; w.i = u & 0xffff0000u; return w.f;
}
__device__ __forceinline__ unsigned short f2bf(float f) {
  union { float ff; unsigned int i; } w; w.ff = f;
  unsigned int x = w.i;
  return (unsigned short)((x + 0x7fffu + ((x >> 16) & 1u)) >> 16);  // RNE
}

// One-shot prep: x -> bf16; weights -> bf16 transposed ([n][k]) so GEMM B
// fragments are contiguous along k.
__global__ __launch_bounds__(256) void prep(
    const float* __restrict__ x, const float* __restrict__ Wq,
    const float* __restrict__ Wkv, const float* __restrict__ Wp,
    unsigned short* __restrict__ xb, unsigned short* __restrict__ WqT,
    unsigned short* __restrict__ WkvT, unsigned short* __restrict__ WpT)
{
  const int XU = NVOX * CDIM / 8;  // 526848 units of 8 floats
  const int t = blockIdx.x * 256 + threadIdx.x;
  if (t < XU) {
    const float4 a = ((const float4*)x)[t * 2];
    const float4 b = ((const float4*)x)[t * 2 + 1];
    unsigned short o[8] = {f2bf(a.x), f2bf(a.y), f2bf(a.z), f2bf(a.w),
                           f2bf(b.x), f2bf(b.y), f2bf(b.z), f2bf(b.w)};
    *(uint4*)(&xb[t * 8]) = *(const uint4*)o;
  } else {
    int u = t - XU;
    if (u < CDIM * CDIM) {
      const int n = u / CDIM, k = u % CDIM;
      WqT[u] = f2bf(Wq[k * CDIM + n]);
    } else if ((u -= CDIM * CDIM) < 2 * CDIM * CDIM) {
      const int n = u / CDIM, k = u % CDIM;
      WkvT[u] = f2bf(Wkv[k * 2 * CDIM + n]);
    } else {
      u -= 2 * CDIM * CDIM;
      const int n = u / CDIM, k = u % CDIM;
      WpT[u] = f2bf(Wp[k * CDIM + n]);
    }
  }
}

// C[M,N] = (A @ B + bias) * alpha with A [M][192] bf16, Bt [N][192] bf16.
// 64x64 block tile, 4 waves each 32x32, K=192 resident in LDS.
template<int OUT_BF16>
__global__ __launch_bounds__(256) void gemm_bf16(
    const unsigned short* __restrict__ A,
    const unsigned short* __restrict__ Bt,
    const float* __restrict__ bias,
    void* __restrict__ Cout,
    int N, float alpha)
{
  __shared__ unsigned short As[64 * 200];
  __shared__ unsigned short Bs[64 * 200];
  const int tid = threadIdx.x;
  const int n0 = blockIdx.x * 64;
  const int m0 = blockIdx.y * 64;

#pragma unroll
  for (int u = tid; u < 1536; u += 256) {  // 64 rows x 24 16B-units
    const int row = u / 24, c = (u % 24) * 8;
    *(uint4*)(&As[row * 200 + c]) =
        *(const uint4*)(&A[(size_t)(m0 + row) * CDIM + c]);
    *(uint4*)(&Bs[row * 200 + c]) =
        *(const uint4*)(&Bt[(size_t)(n0 + row) * CDIM + c]);
  }
  __syncthreads();

  const int l = tid & 63, w = tid >> 6;
  const int wm = (w >> 1) * 32, wn = (w & 1) * 32;
  const int lr = l & 15, lk = (l >> 4) * 8;

  f32x4 acc[2][2] = {};
  const unsigned short* pa = &As[(wm + lr) * 200 + lk];
  const unsigned short* pb = &Bs[(wn + lr) * 200 + lk];

#pragma unroll
  for (int k0 = 0; k0 < CDIM; k0 += 32) {
    const bf16x8 a0 = *(const bf16x8*)(pa + k0);
    const bf16x8 a1 = *(const bf16x8*)(pa + 16 * 200 + k0);
    const bf16x8 b0 = *(const bf16x8*)(pb + k0);
    const bf16x8 b1 = *(const bf16x8*)(pb + 16 * 200 + k0);
    acc[0][0] = __builtin_amdgcn_mfma_f32_16x16x32_bf16(a0, b0, acc[0][0], 0, 0, 0);
    acc[0][1] = __builtin_amdgcn_mfma_f32_16x16x32_bf16(a0, b1, acc[0][1], 0, 0, 0);
    acc[1][0] = __builtin_amdgcn_mfma_f32_16x16x32_bf16(a1, b0, acc[1][0], 0, 0, 0);
    acc[1][1] = __builtin_amdgcn_mfma_f32_16x16x32_bf16(a1, b1, acc[1][1], 0, 0, 0);
  }

  // C/D: col = lane&15, row = (lane>>4)*4 + reg   [m89-verified]
#pragma unroll
  for (int i = 0; i < 2; ++i)
#pragma unroll
    for (int j = 0; j < 2; ++j) {
      const int gc = n0 + wn + j * 16 + lr;
      const float bv = bias[gc];
#pragma unroll
      for (int r = 0; r < 4; ++r) {
        const int gr = m0 + wm + i * 16 + (l >> 4) * 4 + r;
        const float v = (acc[i][j][r] + bv) * alpha;
        if (OUT_BF16)
          ((unsigned short*)Cout)[(size_t)gr * N + gc] = f2bf(v);
        else
          ((float*)Cout)[(size_t)gr * N + gc] = v;
      }
    }
}

// x-line attention: one wave per (z, y, head). Lane = (x in 0..27, g half-head);
// lane owns 24 channels. Per (dz,dy) neighbor line: 6 uint4 loads (k+v line),
// dx=+-1 via lane shuffles, online softmax fused with PV accumulate.
// OOB slots (zero-padded k/v): logit = 0 in the denominator -> closed form
// init m=0, s=n_oob. Block = 4 waves = 4 heads of same (z,y): L1 reuse.
// XCD z-slab swizzle: each XCD's kv slab ~3.3 MB fits its 4 MB L2.
__global__ __launch_bounds__(256, 4) void attn3d_line(
    const unsigned short* __restrict__ q,
    const unsigned short* __restrict__ kv,
    unsigned short* __restrict__ y)
{
  const int bid = blockIdx.x;
  const int zy = (bid & 7) * 98 + (bid >> 3);   // 784 = 8 * 98, bijective
  const int z = zy / 28, yr = zy % 28;
  const int h = threadIdx.x >> 6;
  const int lane = threadIdx.x & 63;
  const int x = lane & 31;
  const int g = lane >> 5;
  const int xc = x < 28 ? x : 27;               // clamp idle lanes' addresses
  const int cb = h * 48 + g * 24;               // 24 ch = 12 uints = 3 uint4
  const int vox = (z * 28 + yr) * 28 + xc;

  // q fragment (already scaled by hc^-0.5 in the Q-GEMM)
  float qf[24];
  {
    const uint4* qp = (const uint4*)(q + (size_t)vox * CDIM + cb);
    const uint4 a = qp[0], b = qp[1], c = qp[2];
    const unsigned int uu[12] = {a.x, a.y, a.z, a.w, b.x, b.y, b.z, b.w,
                                 c.x, c.y, c.z, c.w};
#pragma unroll
    for (int i = 0; i < 12; ++i) { qf[2*i] = blo(uu[i]); qf[2*i+1] = bhi(uu[i]); }
  }

  const int nx = 3 - (x == 0) - (x == 27);
  const int nyv = 3 - (yr == 0) - (yr == 27);
  const int nzv = 3 - (z == 0) - (z == 27);
  const int noob = 27 - nx * nyv * nzv;
  float m = noob ? 0.f : -INFINITY;
  float s = (float)noob;
  float out[24];
#pragma unroll
  for (int i = 0; i < 24; ++i) out[i] = 0.f;

  const int lm1 = lane - 1, lp1 = lane + 1;
  const bool okm = (x > 0), okp = (x < 27);

  for (int dz = -1; dz <= 1; ++dz) {
    const int zz = z + dz;
    if ((unsigned)zz >= 28u) continue;          // wave-uniform
    for (int dy = -1; dy <= 1; ++dy) {
      const int yv = yr + dy;
      if ((unsigned)yv >= 28u) continue;        // wave-uniform
      const unsigned short* row =
          kv + (size_t)((zz * 28 + yv) * 28 + xc) * (2 * CDIM) + cb;
      const uint4* kp = (const uint4*)row;
      const uint4* vp = (const uint4*)(row + CDIM);
      const uint4 ka = kp[0], kb = kp[1], kc = kp[2];
      const uint4 va = vp[0], vb = vp[1], vc = vp[2];
      const unsigned int ku[12] = {ka.x, ka.y, ka.z, ka.w, kb.x, kb.y, kb.z,
                                   kb.w, kc.x, kc.y, kc.z, kc.w};
      const unsigned int vu[12] = {va.x, va.y, va.z, va.w, vb.x, vb.y, vb.z,
                                   vb.w, vc.x, vc.y, vc.z, vc.w};

      float p0 = 0.f, p1 = 0.f, p2 = 0.f;
#pragma unroll
      for (int i = 0; i < 12; ++i) {
        p1 += qf[2*i] * blo(ku[i]) + qf[2*i+1] * bhi(ku[i]);
        unsigned int t = (unsigned int)__shfl((int)ku[i], lm1);
        p0 += qf[2*i] * blo(t) + qf[2*i+1] * bhi(t);
        t = (unsigned int)__shfl((int)ku[i], lp1);
        p2 += qf[2*i] * blo(t) + qf[2*i+1] * bhi(t);
      }
      // combine the two half-head partials (g=0 <-> g=1 at lane^32)
      p0 += __shfl_xor(p0, 32);
      p1 += __shfl_xor(p1, 32);
      p2 += __shfl_xor(p2, 32);

      const float l0 = okm ? p0 : -INFINITY;
      const float l2 = okp ? p2 : -INFINITY;
      const float nm = fmaxf(m, fmaxf(p1, fmaxf(l0, l2)));
      const float sc = __expf(m - nm);
      const float w0 = okm ? __expf(p0 - nm) : 0.f;
      const float w1 = __expf(p1 - nm);
      const float w2 = okp ? __expf(p2 - nm) : 0.f;
      s = s * sc + w0 + w1 + w2;
      m = nm;

#pragma unroll
      for (int i = 0; i < 12; ++i) {
        const unsigned int am = (unsigned int)__shfl((int)vu[i], lm1);
        const unsigned int ap = (unsigned int)__shfl((int)vu[i], lp1);
        out[2*i]   = out[2*i]   * sc + w0 * blo(am) + w1 * blo(vu[i]) + w2 * blo(ap);
        out[2*i+1] = out[2*i+1] * sc + w0 * bhi(am) + w1 * bhi(vu[i]) + w2 * bhi(ap);
      }
    }
  }

  if (x < 28) {
    const float inv = 1.f / s;
    unsigned int ou[12];
#pragma unroll
    for (int i = 0; i < 12; ++i)
      ou[i] = (unsigned int)f2bf(out[2*i] * inv) |
              ((unsigned int)f2bf(out[2*i+1] * inv) << 16);
    uint4* yp = (uint4*)(y + (size_t)vox * CDIM + cb);
    yp[0] = make_uint4(ou[0], ou[1], ou[2], ou[3]);
    yp[1] = make_uint4(ou[4], ou[5], ou[6], ou[7]);
    yp[2] = make_uint4(ou[8], ou[9], ou[10], ou[11]);
  }
}

extern "C" void kernel_launch(void* const* d_in, const int* in_sizes, int n_in,
                              void* d_out, int out_size, void* d_ws, size_t ws_size,
                              hipStream_t stream) {
  const float* x   = (const float*)d_in[0];
  const float* Wq  = (const float*)d_in[1];
  const float* bq  = (const float*)d_in[2];
  const float* Wkv = (const float*)d_in[3];
  const float* bkv = (const float*)d_in[4];
  const float* Wp  = (const float*)d_in[5];
  const float* bp  = (const float*)d_in[6];
  float* out = (float*)d_out;

  unsigned short* xb   = (unsigned short*)d_ws;
  unsigned short* WqT  = xb + (size_t)NVOX * CDIM;
  unsigned short* WkvT = WqT + CDIM * CDIM;
  unsigned short* WpT  = WkvT + 2 * CDIM * CDIM;
  unsigned short* qb   = WpT + CDIM * CDIM;
  unsigned short* kvb  = qb + (size_t)NVOX * CDIM;
  unsigned short* yb   = kvb + (size_t)NVOX * 2 * CDIM;

  const float scale = 1.0f / sqrtf(48.0f);

  // total prep threads: NVOX*192/8 + 4*192*192 = 526848 + 147456 = 674304
  prep<<<674304 / 256, 256, 0, stream>>>(x, Wq, Wkv, Wp, xb, WqT, WkvT, WpT);

  gemm_bf16<1><<<dim3(CDIM / 64, NVOX / 64), 256, 0, stream>>>(
      xb, WqT, bq, qb, CDIM, scale);
  gemm_bf16<1><<<dim3(2 * CDIM / 64, NVOX / 64), 256, 0, stream>>>(
      xb, WkvT, bkv, kvb, 2 * CDIM, 1.0f);
  attn3d_line<<<DD * DD, 256, 0, stream>>>(qb, kvb, yb);
  gemm_bf16<0><<<dim3(CDIM / 64, NVOX / 64), 256, 0, stream>>>(
      yb, WpT, bp, out, CDIM, 1.0f);
}

// Round 6
// 146.924 us; speedup vs baseline: 1.8117x; 1.0039x over previous
//
#include <hip/hip_runtime.h>
#include <math.h>

#define CDIM 192
#define DD 28
#define NVOX (DD * DD * DD)   // 21952

typedef __attribute__((ext_vector_type(8))) short bf16x8;
typedef __attribute__((ext_vector_type(4))) float f32x4;

__device__ __forceinline__ float blo(unsigned int u) {
  union { unsigned int i; float f; } w; w.i = u << 16; return w.f;
}
__device__ __forceinline__ float bhi(unsigned int u) {
  union { unsigned int i; float f; } w; w.i = u & 0xffff0000u; return w.f;
}
__device__ __forceinline__ unsigned short f2bf(float f) {
  union { float ff; unsigned int i; } w; w.ff = f;
  unsigned int x = w.i;
  return (unsigned short)((x + 0x7fffu + ((x >> 16) & 1u)) >> 16);  // RNE
}

// prep: weights -> bf16, transposed to [n][k]; scale folded into Wq/bq.
// WqkvT is [576][192]: rows 0..191 = Wq^T * scale, rows 192..575 = Wkv^T.
__global__ __launch_bounds__(256) void prep_w(
    const float* __restrict__ Wq, const float* __restrict__ Wkv,
    const float* __restrict__ Wp, const float* __restrict__ bq,
    const float* __restrict__ bkv,
    unsigned short* __restrict__ WqkvT, unsigned short* __restrict__ WpT,
    float* __restrict__ biasAll, float scale)
{
  int t = blockIdx.x * 256 + threadIdx.x;
  if (t < 576 * CDIM) {
    const int n = t / CDIM, k = t % CDIM;
    const float v = (n < CDIM) ? Wq[k * CDIM + n] * scale
                               : Wkv[k * 2 * CDIM + (n - CDIM)];
    WqkvT[t] = f2bf(v);
    return;
  }
  t -= 576 * CDIM;
  if (t < CDIM * CDIM) {
    const int n = t / CDIM, k = t % CDIM;
    WpT[t] = f2bf(Wp[k * CDIM + n]);
    return;
  }
  t -= CDIM * CDIM;
  if (t < 576)
    biasAll[t] = (t < CDIM) ? bq[t] * scale : bkv[t - CDIM];
}

// Fused QKV GEMM: [q|k|v] = x @ WqkvT^T + biasAll. A (fp32) is converted to
// bf16 during LDS staging and loaded ONCE per block; loop over column tiles
// (y-split 2 for load balance: by=0 -> tiles 0,2,4,6,8; by=1 -> 1,3,5,7).
__global__ __launch_bounds__(256) void gemm_qkv(
    const float* __restrict__ X,            // [M][192] fp32
    const unsigned short* __restrict__ Bt,  // [576][192] bf16
    const float* __restrict__ biasAll,      // [576]
    unsigned short* __restrict__ qb,        // [M][192]
    unsigned short* __restrict__ kvb)       // [M][384]
{
  __shared__ unsigned short As[64 * 200];
  __shared__ unsigned short Bs[64 * 200];
  const int tid = threadIdx.x;
  const int m0 = blockIdx.x * 64;
  const int by = blockIdx.y;

#pragma unroll
  for (int u = tid; u < 1536; u += 256) {  // 64 rows x 24 8-elem units
    const int row = u / 24, c = (u % 24) * 8;
    const float4 f0 = *(const float4*)(&X[(size_t)(m0 + row) * CDIM + c]);
    const float4 f1 = *(const float4*)(&X[(size_t)(m0 + row) * CDIM + c + 4]);
    unsigned short o[8] = {f2bf(f0.x), f2bf(f0.y), f2bf(f0.z), f2bf(f0.w),
                           f2bf(f1.x), f2bf(f1.y), f2bf(f1.z), f2bf(f1.w)};
    *(uint4*)(&As[row * 200 + c]) = *(const uint4*)o;
  }

  const int l = tid & 63, w = tid >> 6;
  const int wm = (w >> 1) * 32, wn = (w & 1) * 32;
  const int lr = l & 15, lk = (l >> 4) * 8;
  const unsigned short* pa = &As[(wm + lr) * 200 + lk];
  const unsigned short* pb = &Bs[(wn + lr) * 200 + lk];

  for (int nt = by; nt < 9; nt += 2) {
    const int n0 = nt * 64;
    __syncthreads();  // 1st iter: As ready; later: Bs readers done
#pragma unroll
    for (int u = tid; u < 1536; u += 256) {
      const int row = u / 24, c = (u % 24) * 8;
      *(uint4*)(&Bs[row * 200 + c]) =
          *(const uint4*)(&Bt[(size_t)(n0 + row) * CDIM + c]);
    }
    __syncthreads();

    f32x4 acc[2][2] = {};
#pragma unroll
    for (int k0 = 0; k0 < CDIM; k0 += 32) {
      const bf16x8 a0 = *(const bf16x8*)(pa + k0);
      const bf16x8 a1 = *(const bf16x8*)(pa + 16 * 200 + k0);
      const bf16x8 b0 = *(const bf16x8*)(pb + k0);
      const bf16x8 b1 = *(const bf16x8*)(pb + 16 * 200 + k0);
      acc[0][0] = __builtin_amdgcn_mfma_f32_16x16x32_bf16(a0, b0, acc[0][0], 0, 0, 0);
      acc[0][1] = __builtin_amdgcn_mfma_f32_16x16x32_bf16(a0, b1, acc[0][1], 0, 0, 0);
      acc[1][0] = __builtin_amdgcn_mfma_f32_16x16x32_bf16(a1, b0, acc[1][0], 0, 0, 0);
      acc[1][1] = __builtin_amdgcn_mfma_f32_16x16x32_bf16(a1, b1, acc[1][1], 0, 0, 0);
    }

    // C/D: col = lane&15, row = (lane>>4)*4 + reg
#pragma unroll
    for (int i = 0; i < 2; ++i)
#pragma unroll
      for (int j = 0; j < 2; ++j) {
        const int gc = n0 + wn + j * 16 + lr;
        const float bv = biasAll[gc];
#pragma unroll
        for (int r = 0; r < 4; ++r) {
          const int gr = m0 + wm + i * 16 + (l >> 4) * 4 + r;
          const float v = acc[i][j][r] + bv;
          if (gc < CDIM)
            qb[(size_t)gr * CDIM + gc] = f2bf(v);
          else
            kvb[(size_t)gr * 2 * CDIM + (gc - CDIM)] = f2bf(v);
        }
      }
  }
}

__device__ __forceinline__ void load_row(const unsigned short* rp,
    uint4& K0, uint4& K1, uint4& K2, uint4& V0, uint4& V1, uint4& V2) {
  const uint4* kp = (const uint4*)rp;
  const uint4* vp = (const uint4*)(rp + CDIM);
  K0 = kp[0]; K1 = kp[1]; K2 = kp[2];
  V0 = vp[0]; V1 = vp[1]; V2 = vp[2];
}

__device__ __forceinline__ void do_row(
    uint4 K0, uint4 K1, uint4 K2, uint4 V0, uint4 V1, uint4 V2,
    const float* __restrict__ qf, float* __restrict__ out,
    float& m, float& s, int lm1, int lp1, bool okm, bool okp) {
  const unsigned int ku[12] = {K0.x, K0.y, K0.z, K0.w, K1.x, K1.y, K1.z, K1.w,
                               K2.x, K2.y, K2.z, K2.w};
  const unsigned int vu[12] = {V0.x, V0.y, V0.z, V0.w, V1.x, V1.y, V1.z, V1.w,
                               V2.x, V2.y, V2.z, V2.w};
  float p0 = 0.f, p1 = 0.f, p2 = 0.f;
#pragma unroll
  for (int i = 0; i < 12; ++i) {
    p1 += qf[2*i] * blo(ku[i]) + qf[2*i+1] * bhi(ku[i]);
    unsigned int t = (unsigned int)__shfl((int)ku[i], lm1);
    p0 += qf[2*i] * blo(t) + qf[2*i+1] * bhi(t);
    t = (unsigned int)__shfl((int)ku[i], lp1);
    p2 += qf[2*i] * blo(t) + qf[2*i+1] * bhi(t);
  }
  p0 += __shfl_xor(p0, 32);
  p1 += __shfl_xor(p1, 32);
  p2 += __shfl_xor(p2, 32);
  const float l0 = okm ? p0 : -INFINITY;
  const float l2 = okp ? p2 : -INFINITY;
  const float nm = fmaxf(m, fmaxf(p1, fmaxf(l0, l2)));
  const float sc = __expf(m - nm);
  const float w0 = okm ? __expf(p0 - nm) : 0.f;
  const float w1 = __expf(p1 - nm);
  const float w2 = okp ? __expf(p2 - nm) : 0.f;
  s = s * sc + w0 + w1 + w2;
  m = nm;
#pragma unroll
  for (int i = 0; i < 12; ++i) {
    const unsigned int am = (unsigned int)__shfl((int)vu[i], lm1);
    const unsigned int ap = (unsigned int)__shfl((int)vu[i], lp1);
    out[2*i]   = out[2*i]   * sc + w0 * blo(am) + w1 * blo(vu[i]) + w2 * blo(ap);
    out[2*i+1] = out[2*i+1] * sc + w0 * bhi(am) + w1 * bhi(vu[i]) + w2 * bhi(ap);
  }
}

// x-line attention, depth-2 register prefetch. One wave per (z,y,head);
// lane = (x, half-head g); lane owns 24 channels. 9 (dz,dy) rows fully
// unrolled; loads use clamped (always-valid) addresses so row i+1's load
// issues before row i's compute; invalid rows masked out of the update.
// OOB window slots: logit 0 in denominator -> closed-form init m=0,s=noob.
__global__ __launch_bounds__(256) void attn3d_line(
    const unsigned short* __restrict__ q,
    const unsigned short* __restrict__ kv,
    unsigned short* __restrict__ y)
{
  const int bid = blockIdx.x;
  const int zy = (bid & 7) * 98 + (bid >> 3);   // 784 = 8*98 bijective
  const int z = zy / 28, yr = zy % 28;
  const int h = threadIdx.x >> 6;
  const int lane = threadIdx.x & 63;
  const int x = lane & 31;
  const int g = lane >> 5;
  const int xc = x < 28 ? x : 27;
  const int cb = h * 48 + g * 24;
  const int vox = (z * 28 + yr) * 28 + xc;

  float qf[24];
  {
    const uint4* qp = (const uint4*)(q + (size_t)vox * CDIM + cb);
    const uint4 a = qp[0], b = qp[1], c = qp[2];
    const unsigned int uu[12] = {a.x, a.y, a.z, a.w, b.x, b.y, b.z, b.w,
                                 c.x, c.y, c.z, c.w};
#pragma unroll
    for (int i = 0; i < 12; ++i) { qf[2*i] = blo(uu[i]); qf[2*i+1] = bhi(uu[i]); }
  }

  const int nx = 3 - (x == 0) - (x == 27);
  const int nyv = 3 - (yr == 0) - (yr == 27);
  const int nzv = 3 - (z == 0) - (z == 27);
  const int noob = 27 - nx * nyv * nzv;
  float m = noob ? 0.f : -INFINITY;
  float s = (float)noob;
  float out[24];
#pragma unroll
  for (int i = 0; i < 24; ++i) out[i] = 0.f;

  const int lm1 = lane - 1, lp1 = lane + 1;
  const bool okm = (x > 0), okp = (x < 27);

  const unsigned short* rbase = kv + (size_t)xc * 384 + cb;
  const int zm = z > 0 ? z - 1 : 0,  zp = z < 27 ? z + 1 : 27;
  const int ym = yr > 0 ? yr - 1 : 0, yp = yr < 27 ? yr + 1 : 27;
  const int r0 = (zm*28+ym)*10752, r1 = (zm*28+yr)*10752, r2 = (zm*28+yp)*10752;
  const int r3 = (z *28+ym)*10752, r4 = (z *28+yr)*10752, r5 = (z *28+yp)*10752;
  const int r6 = (zp*28+ym)*10752, r7 = (zp*28+yr)*10752, r8 = (zp*28+yp)*10752;
  const bool vz0 = z > 0, vz2 = z < 27, vy0 = yr > 0, vy2 = yr < 27;
  const bool v0 = vz0 && vy0, v1 = vz0, v2 = vz0 && vy2;
  const bool v3 = vy0,                  v5 = vy2;
  const bool v6 = vz2 && vy0, v7 = vz2, v8 = vz2 && vy2;

  uint4 Ak0, Ak1, Ak2, Av0, Av1, Av2;
  uint4 Bk0, Bk1, Bk2, Bv0, Bv1, Bv2;

  load_row(rbase + r0, Ak0, Ak1, Ak2, Av0, Av1, Av2);
  load_row(rbase + r1, Bk0, Bk1, Bk2, Bv0, Bv1, Bv2);
  if (v0) do_row(Ak0, Ak1, Ak2, Av0, Av1, Av2, qf, out, m, s, lm1, lp1, okm, okp);
  load_row(rbase + r2, Ak0, Ak1, Ak2, Av0, Av1, Av2);
  if (v1) do_row(Bk0, Bk1, Bk2, Bv0, Bv1, Bv2, qf, out, m, s, lm1, lp1, okm, okp);
  load_row(rbase + r3, Bk0, Bk1, Bk2, Bv0, Bv1, Bv2);
  if (v2) do_row(Ak0, Ak1, Ak2, Av0, Av1, Av2, qf, out, m, s, lm1, lp1, okm, okp);
  load_row(rbase + r4, Ak0, Ak1, Ak2, Av0, Av1, Av2);
  if (v3) do_row(Bk0, Bk1, Bk2, Bv0, Bv1, Bv2, qf, out, m, s, lm1, lp1, okm, okp);
  load_row(rbase + r5, Bk0, Bk1, Bk2, Bv0, Bv1, Bv2);
  do_row(Ak0, Ak1, Ak2, Av0, Av1, Av2, qf, out, m, s, lm1, lp1, okm, okp);  // center
  load_row(rbase + r6, Ak0, Ak1, Ak2, Av0, Av1, Av2);
  if (v5) do_row(Bk0, Bk1, Bk2, Bv0, Bv1, Bv2, qf, out, m, s, lm1, lp1, okm, okp);
  load_row(rbase + r7, Bk0, Bk1, Bk2, Bv0, Bv1, Bv2);
  if (v6) do_row(Ak0, Ak1, Ak2, Av0, Av1, Av2, qf, out, m, s, lm1, lp1, okm, okp);
  load_row(rbase + r8, Ak0, Ak1, Ak2, Av0, Av1, Av2);
  if (v7) do_row(Bk0, Bk1, Bk2, Bv0, Bv1, Bv2, qf, out, m, s, lm1, lp1, okm, okp);
  if (v8) do_row(Ak0, Ak1, Ak2, Av0, Av1, Av2, qf, out, m, s, lm1, lp1, okm, okp);

  if (x < 28) {
    const float inv = 1.f / s;
    unsigned int ou[12];
#pragma unroll
    for (int i = 0; i < 12; ++i)
      ou[i] = (unsigned int)f2bf(out[2*i] * inv) |
              ((unsigned int)f2bf(out[2*i+1] * inv) << 16);
    uint4* yp = (uint4*)(y + (size_t)vox * CDIM + cb);
    yp[0] = make_uint4(ou[0], ou[1], ou[2], ou[3]);
    yp[1] = make_uint4(ou[4], ou[5], ou[6], ou[7]);
    yp[2] = make_uint4(ou[8], ou[9], ou[10], ou[11]);
  }
}

// Output projection: out = y @ WpT^T + bp, fp32 out. 64x64 tiles, grid (3,343).
__global__ __launch_bounds__(256) void gemm_out(
    const unsigned short* __restrict__ A,
    const unsigned short* __restrict__ Bt,
    const float* __restrict__ bias,
    float* __restrict__ C)
{
  __shared__ unsigned short As[64 * 200];
  __shared__ unsigned short Bs[64 * 200];
  const int tid = threadIdx.x;
  const int n0 = blockIdx.x * 64;
  const int m0 = blockIdx.y * 64;

#pragma unroll
  for (int u = tid; u < 1536; u += 256) {
    const int row = u / 24, c = (u % 24) * 8;
    *(uint4*)(&As[row * 200 + c]) =
        *(const uint4*)(&A[(size_t)(m0 + row) * CDIM + c]);
    *(uint4*)(&Bs[row * 200 + c]) =
        *(const uint4*)(&Bt[(size_t)(n0 + row) * CDIM + c]);
  }
  __syncthreads();

  const int l = tid & 63, w = tid >> 6;
  const int wm = (w >> 1) * 32, wn = (w & 1) * 32;
  const int lr = l & 15, lk = (l >> 4) * 8;

  f32x4 acc[2][2] = {};
  const unsigned short* pa = &As[(wm + lr) * 200 + lk];
  const unsigned short* pb = &Bs[(wn + lr) * 200 + lk];

#pragma unroll
  for (int k0 = 0; k0 < CDIM; k0 += 32) {
    const bf16x8 a0 = *(const bf16x8*)(pa + k0);
    const bf16x8 a1 = *(const bf16x8*)(pa + 16 * 200 + k0);
    const bf16x8 b0 = *(const bf16x8*)(pb + k0);
    const bf16x8 b1 = *(const bf16x8*)(pb + 16 * 200 + k0);
    acc[0][0] = __builtin_amdgcn_mfma_f32_16x16x32_bf16(a0, b0, acc[0][0], 0, 0, 0);
    acc[0][1] = __builtin_amdgcn_mfma_f32_16x16x32_bf16(a0, b1, acc[0][1], 0, 0, 0);
    acc[1][0] = __builtin_amdgcn_mfma_f32_16x16x32_bf16(a1, b0, acc[1][0], 0, 0, 0);
    acc[1][1] = __builtin_amdgcn_mfma_f32_16x16x32_bf16(a1, b1, acc[1][1], 0, 0, 0);
  }

#pragma unroll
  for (int i = 0; i < 2; ++i)
#pragma unroll
    for (int j = 0; j < 2; ++j) {
      const int gc = n0 + wn + j * 16 + lr;
      const float bv = bias[gc];
#pragma unroll
      for (int r = 0; r < 4; ++r) {
        const int gr = m0 + wm + i * 16 + (l >> 4) * 4 + r;
        C[(size_t)gr * CDIM + gc] = acc[i][j][r] + bv;
      }
    }
}

extern "C" void kernel_launch(void* const* d_in, const int* in_sizes, int n_in,
                              void* d_out, int out_size, void* d_ws, size_t ws_size,
                              hipStream_t stream) {
  const float* x   = (const float*)d_in[0];
  const float* Wq  = (const float*)d_in[1];
  const float* bq  = (const float*)d_in[2];
  const float* Wkv = (const float*)d_in[3];
  const float* bkv = (const float*)d_in[4];
  const float* Wp  = (const float*)d_in[5];
  const float* bp  = (const float*)d_in[6];
  float* out = (float*)d_out;

  unsigned short* WqkvT = (unsigned short*)d_ws;          // 576*192
  unsigned short* WpT   = WqkvT + 576 * CDIM;             // 192*192
  float*          biasA = (float*)(WpT + CDIM * CDIM);    // 576 floats
  unsigned short* qb    = (unsigned short*)(biasA + 576); // NVOX*192
  unsigned short* kvb   = qb + (size_t)NVOX * CDIM;       // NVOX*384
  unsigned short* yb    = kvb + (size_t)NVOX * 2 * CDIM;  // NVOX*192

  const float scale = 1.0f / sqrtf(48.0f);

  // prep threads: 576*192 + 192*192 + 576 = 148032
  prep_w<<<(148032 + 255) / 256, 256, 0, stream>>>(
      Wq, Wkv, Wp, bq, bkv, WqkvT, WpT, biasA, scale);

  gemm_qkv<<<dim3(NVOX / 64, 2), 256, 0, stream>>>(x, WqkvT, biasA, qb, kvb);
  attn3d_line<<<DD * DD, 256, 0, stream>>>(qb, kvb, yb);
  gemm_out<<<dim3(3, NVOX / 64), 256, 0, stream>>>(yb, WpT, bp, out);
}